// Round 10
// baseline (114.280 us; speedup 1.0000x reference)
//
#include <hip/hip_runtime.h>
#include <math.h>

#define NB 4
#define IH 128
#define IW 128
#define GH 256
#define GW 256
#define NGAUSS (NB * GH * GW)   // 262144

// d_ws layout (floats):
// [0, 2592)          weff [4][24][27]
// [2592, 2688)       beff [4][24]
// [2688, +2N)        pos  float2[N]  (cy, cx)
// [POS+2N, +4N)      col  float4[N]  (cr, cg, cb, 0)   total ~6.3 MB
#define WEFF_FLOATS (4 * 24 * 27)
#define BEFF_FLOATS (4 * 24)
#define POS_OFF 2688
#define COL_OFF (POS_OFF + 2 * NGAUSS)

// gather tiling: 16x16 px tile; candidate centers at ww-px,hh-py in [-2,+4]
// (exact: |2*tanh|<2 and rr < ln(255)/2 -> |dx|,|dy| < 1.664).
#define TSX 16
#define TSY 16
#define GR 22              // 16 + 6 live region side
#define NREG (GR * GR)     // 484
#define RR_MAX 2.770360f   // ln(255)/2 : alpha > 1/255  <=>  rr < RR_MAX
#define EXP2C (-2.8853900818f)  // -2/ln(2) : exp(-2rr) = exp2(EXP2C*rr)

__device__ __forceinline__ float fast_tanh(float x) {
  return 1.f - 2.f / (__expf(2.f * x) + 1.f);
}
__device__ __forceinline__ float clamp01(float v) {
  return fminf(1.f, fmaxf(0.f, v));
}

// One block per parity p: fold w_head x (pixel ops) x w_enc into
// W_eff[p][24][27], b_eff[p][24].
__global__ __launch_bounds__(256) void weff_kernel(
    const float* __restrict__ w_enc, const float* __restrict__ b_enc,
    const float* __restrict__ w_head, const float* __restrict__ b_head,
    float* __restrict__ weff, float* __restrict__ beff) {
  __shared__ float sWH[24 * 256];
  __shared__ float sWE[256 * 27];
  __shared__ float sBE[256];

  int tid = (int)threadIdx.x;
  int p = (int)blockIdx.x;          // p = ph*2 + pw
  int ph = p >> 1, pw = p & 1;

  for (int i = tid; i < 24 * 256; i += 256) sWH[i] = w_head[i];
  {
    int hc = tid;
    int ch = ((hc >> 2) << 4) + (2 * ph + ((hc >> 1) & 1)) * 4 + (2 * pw + (hc & 1));
    for (int t = 0; t < 27; ++t) sWE[hc * 27 + t] = w_enc[ch * 27 + t];
    sBE[hc] = b_enc[ch];
  }
  __syncthreads();

  for (int j = tid; j < 24 * 27; j += 256) {
    int o = j / 27, t = j % 27;
    float a = 0.f;
    for (int hc = 0; hc < 256; ++hc) a = fmaf(sWH[o * 256 + hc], sWE[hc * 27 + t], a);
    weff[p * (24 * 27) + j] = a;
  }
  if (tid < 24) {
    float a = b_head[tid];
    for (int hc = 0; hc < 256; ++hc) a = fmaf(sWH[tid * 256 + hc], sBE[hc], a);
    beff[p * 24 + tid] = a;
  }
}

// 512 blocks; each thread evaluates TWO same-parity gaussians (ww, ww+16),
// sharing the LDS weight reads. Each gaussian computed exactly once.
__global__ __launch_bounds__(256, 4) void gauss_kernel(
    const float* __restrict__ inp, const float* __restrict__ ws_ro,
    float* __restrict__ ws) {
  __shared__ float sW[4 * 24 * 28];   // k padded 27 -> 28 for float4 reads
  __shared__ float sB[BEFF_FLOATS];

  int tid = (int)threadIdx.x;
  for (int i = tid; i < 4 * 24 * 28; i += 256) {
    int row = i / 28, k = i - row * 28;   // row = p*24+o
    sW[i] = (k < 27) ? ws_ro[row * 27 + k] : 0.f;
  }
  for (int i = tid; i < BEFF_FLOATS; i += 256) sB[i] = ws_ro[WEFF_FLOATS + i];
  __syncthreads();

  int bid = (int)blockIdx.x;
  int b = bid >> 7;
  int t = bid & 127;                 // 16 y-tiles x 8 x-tiles of 16x32
  int TYg = (t >> 3) * 16;
  int TXg = (t & 7) * 32;
  int hh = TYg + (tid >> 4);
  int ww0 = TXg + (tid & 15);        // second gaussian at ww0+16 (same parity)
  int p = (hh & 1) * 2 + (ww0 & 1);
  int hs = hh >> 1, ws0 = ww0 >> 1;  // ws1 = ws0 + 8

  const float* ib = inp + b * 3 * IH * IW;
  float in0[28], in1[28];
  in0[27] = 0.f; in1[27] = 0.f;
  #pragma unroll
  for (int cin = 0; cin < 3; ++cin) {
    #pragma unroll
    for (int ky = 0; ky < 3; ++ky) {
      int y = hs + ky - 1;
      bool yok = (y >= 0 && y < IH);
      #pragma unroll
      for (int kx = 0; kx < 3; ++kx) {
        int x0 = ws0 + kx - 1;
        int x1 = x0 + 8;             // >= 7, never < 0
        float v0 = 0.f, v1 = 0.f;
        if (yok && x0 >= 0 && x0 < IW) v0 = ib[(cin * IH + y) * IW + x0];
        if (yok && x1 < IW) v1 = ib[(cin * IH + y) * IW + x1];
        in0[cin * 9 + ky * 3 + kx] = v0;
        in1[cin * 9 + ky * 3 + kx] = v1;
      }
    }
  }

  float a0[24], a1[24];
  #pragma unroll
  for (int o = 0; o < 24; ++o) { float bi = sB[p * 24 + o]; a0[o] = bi; a1[o] = bi; }
  #pragma unroll
  for (int o = 0; o < 24; ++o) {
    const float4* wrow = (const float4*)&sW[(p * 24 + o) * 28];
    #pragma unroll
    for (int kq = 0; kq < 7; ++kq) {
      float4 w = wrow[kq];
      a0[o] = fmaf(in0[kq * 4 + 0], w.x, a0[o]);
      a0[o] = fmaf(in0[kq * 4 + 1], w.y, a0[o]);
      a0[o] = fmaf(in0[kq * 4 + 2], w.z, a0[o]);
      a0[o] = fmaf(in0[kq * 4 + 3], w.w, a0[o]);
      a1[o] = fmaf(in1[kq * 4 + 0], w.x, a1[o]);
      a1[o] = fmaf(in1[kq * 4 + 1], w.y, a1[o]);
      a1[o] = fmaf(in1[kq * 4 + 2], w.z, a1[o]);
      a1[o] = fmaf(in1[kq * 4 + 3], w.w, a1[o]);
    }
  }

  float2* posP = (float2*)(ws + POS_OFF);
  float4* colP = (float4*)(ws + COL_OFF);

  #pragma unroll
  for (int which = 0; which < 2; ++which) {
    const float* pr = which ? a1 : a0;
    int ww = which ? (ww0 + 16) : ww0;

    float l0 = pr[5], l1 = pr[11], l2 = pr[17], l3 = pr[23];
    float m = fmaxf(fmaxf(l0, l1), fmaxf(l2, l3));
    float e0 = __expf(l0 - m), e1 = __expf(l1 - m);
    float e2 = __expf(l2 - m), e3 = __expf(l3 - m);
    float inv = 1.f / (e0 + e1 + e2 + e3);
    float w0 = e0 * inv, w1 = e1 * inv, w2 = e2 * inv, w3 = e3 * inv;
    float cr = w0 * pr[0] + w1 * pr[6] + w2 * pr[12] + w3 * pr[18];
    float cg = w0 * pr[1] + w1 * pr[7] + w2 * pr[13] + w3 * pr[19];
    float cb = w0 * pr[2] + w1 * pr[8] + w2 * pr[14] + w3 * pr[20];
    float ox = w0 * fast_tanh(pr[3]) + w1 * fast_tanh(pr[9]) +
               w2 * fast_tanh(pr[15]) + w3 * fast_tanh(pr[21]);
    float oy = w0 * fast_tanh(pr[4]) + w1 * fast_tanh(pr[10]) +
               w2 * fast_tanh(pr[16]) + w3 * fast_tanh(pr[22]);

    // reference-order coordinate math (w=h=128, W=H=gw=gh=256)
    float coordx = ((float)ww / 256.f) * 2.f - 1.f;
    float coordy = ((float)hh / 256.f) * 2.f - 1.f;
    float x_ndc = coordx + 2.f * ox / 128.f - 1.f / 256.f;
    float y_ndc = coordy + 2.f * oy / 128.f - 1.f / 256.f;
    float cx = 0.5f * ((x_ndc + 1.f) * 256.f - 1.f);
    float cy = 0.5f * ((y_ndc + 1.f) * 256.f - 1.f);

    int g = (b << 16) | (hh << 8) | ww;
    posP[g] = make_float2(cy, cx);
    colP[g] = make_float4(cr, cg, cb, 0.f);
  }
}

// 1024 blocks; 16x16 px tile, 1 px/thread, exact 7x7 candidate window with
// rr-threshold test (== reference alpha test). No atomics.
__global__ __launch_bounds__(256, 4) void gather_kernel(
    const float* __restrict__ ws, float* __restrict__ out) {
  __shared__ float2 sPos[NREG];
  __shared__ float4 sCol[NREG];

  int tid = (int)threadIdx.x;
  int bid = (int)blockIdx.x;
  int b = bid >> 8;
  int t = bid & 255;
  int TY = (t >> 4) * TSY;
  int TX = (t & 15) * TSX;
  const float2* posP = (const float2*)(ws + POS_OFF);
  const float4* colP = (const float4*)(ws + COL_OFF);

  for (int i = tid; i < NREG; i += 256) {
    int r = i / GR, c = i - r * GR;
    int hh = TY - 2 + r, ww = TX - 2 + c;
    if ((unsigned)hh < GH && (unsigned)ww < GW) {
      int g = (b << 16) | (hh << 8) | ww;
      sPos[i] = posP[g];
      sCol[i] = colP[g];
    } else {
      sPos[i] = make_float2(1e9f, 1e9f);
      sCol[i] = make_float4(0.f, 0.f, 0.f, 0.f);
    }
  }
  __syncthreads();

  int pxl = tid & 15, pyl = tid >> 4;
  float fpx = (float)(TX + pxl), fpy = (float)(TY + pyl);
  float ar = 0.f, ag = 0.f, ab = 0.f;

  #pragma unroll
  for (int ry = 0; ry < 7; ++ry) {
    int base = (pyl + ry) * GR + pxl;
    #pragma unroll
    for (int rx = 0; rx < 7; ++rx) {
      float2 P = sPos[base + rx];
      float dy = fpy - P.x;
      float dx = fpx - P.y;
      float rr = fmaf(dy, dy, dx * dx);
      if (rr < RR_MAX) {
        float al = fminf(0.999f, exp2f(EXP2C * rr));
        float4 C = sCol[base + rx];
        ar = fmaf(al, C.x, ar);
        ag = fmaf(al, C.y, ag);
        ab = fmaf(al, C.z, ab);
      }
    }
  }

  float* ob = out + b * 3 * GH * GW;
  int i0 = (TY + pyl) * GW + (TX + pxl);
  ob[i0] = clamp01(ar);
  ob[GH * GW + i0] = clamp01(ag);
  ob[2 * GH * GW + i0] = clamp01(ab);
}

extern "C" void kernel_launch(void* const* d_in, const int* in_sizes, int n_in,
                              void* d_out, int out_size, void* d_ws, size_t ws_size,
                              hipStream_t stream) {
  const float* inp = (const float*)d_in[0];
  const float* w_enc = (const float*)d_in[1];
  const float* b_enc = (const float*)d_in[2];
  const float* w_head = (const float*)d_in[3];
  const float* b_head = (const float*)d_in[4];
  // d_in[5] = scale (int), hardcoded 2.

  float* ws = (float*)d_ws;
  float* weff = ws;                  // [0, 2592)
  float* beff = ws + WEFF_FLOATS;    // [2592, 2688)

  weff_kernel<<<4, 256, 0, stream>>>(w_enc, b_enc, w_head, b_head, weff, beff);

  gauss_kernel<<<512, 256, 0, stream>>>(inp, ws, ws);

  gather_kernel<<<NB * 256, 256, 0, stream>>>(ws, (float*)d_out);
}

// Round 11
// 100.991 us; speedup vs baseline: 1.1316x; 1.1316x over previous
//
#include <hip/hip_runtime.h>
#include <math.h>

#define NB 4
#define IH 128
#define IW 128
#define GH 256
#define GW 256
#define NGAUSS (NB * GH * GW)   // 262144

// d_ws layout (floats):
// [0, 2592)          weff [4][24][27]
// [2592, 2688)       beff [4][24]
// [2688, +2N)        pos  float2[N]  (cy, cx)
// [POS+2N, +N each)  cr, cg, cb planes
#define WEFF_FLOATS (4 * 24 * 27)
#define BEFF_FLOATS (4 * 24)
#define POS_OFF 2688
#define CR_OFF (POS_OFF + 2 * NGAUSS)
#define CG_OFF (CR_OFF + NGAUSS)
#define CB_OFF (CG_OFF + NGAUSS)

// gather tiling: 16x16 pixel tile; candidate gaussians ww-px,hh-py in [-3,+4].
#define TSX 16
#define TSY 16
#define GR 24              // loaded region side
#define NREG (GR * GR)     // 576
#define RR_MAX 2.770360f   // ln(255)/2 : alpha > 1/255  <=>  rr < RR_MAX
#define EXP2C (-2.8853900818f)  // -2/ln(2) : exp(-2rr) = exp2(EXP2C*rr)

__device__ __forceinline__ float fast_tanh(float x) {
  return 1.f - 2.f / (__expf(2.f * x) + 1.f);
}
__device__ __forceinline__ float clamp01(float v) {
  return fminf(1.f, fmaxf(0.f, v));
}

// One block per parity p: fold w_head x (pixel ops) x w_enc into
// W_eff[p][24][27], b_eff[p][24].
__global__ __launch_bounds__(256) void weff_kernel(
    const float* __restrict__ w_enc, const float* __restrict__ b_enc,
    const float* __restrict__ w_head, const float* __restrict__ b_head,
    float* __restrict__ weff, float* __restrict__ beff) {
  __shared__ float sWH[24 * 256];
  __shared__ float sWE[256 * 27];
  __shared__ float sBE[256];

  int tid = (int)threadIdx.x;
  int p = (int)blockIdx.x;          // p = ph*2 + pw
  int ph = p >> 1, pw = p & 1;

  for (int i = tid; i < 24 * 256; i += 256) sWH[i] = w_head[i];
  {
    int hc = tid;
    int ch = ((hc >> 2) << 4) + (2 * ph + ((hc >> 1) & 1)) * 4 + (2 * pw + (hc & 1));
    for (int t = 0; t < 27; ++t) sWE[hc * 27 + t] = w_enc[ch * 27 + t];
    sBE[hc] = b_enc[ch];
  }
  __syncthreads();

  for (int j = tid; j < 24 * 27; j += 256) {
    int o = j / 27, t = j % 27;
    float a = 0.f;
    for (int hc = 0; hc < 256; ++hc) a = fmaf(sWH[o * 256 + hc], sWE[hc * 27 + t], a);
    weff[p * (24 * 27) + j] = a;
  }
  if (tid < 24) {
    float a = b_head[tid];
    for (int hc = 0; hc < 256; ++hc) a = fmaf(sWH[tid * 256 + hc], sBE[hc], a);
    beff[p * 24 + tid] = a;
  }
}

// 512 blocks; each thread evaluates TWO same-parity gaussians (ww, ww+16),
// sharing the LDS weight reads. Writes pos/color planes (SoA) to ws.
__global__ __launch_bounds__(256) void gauss_kernel(
    const float* __restrict__ inp, const float* __restrict__ ws_ro,
    float* __restrict__ ws) {
  __shared__ float sW[4 * 24 * 28];   // k padded 27 -> 28 for float4 reads
  __shared__ float sB[BEFF_FLOATS];

  int tid = (int)threadIdx.x;
  for (int i = tid; i < 4 * 24 * 28; i += 256) {
    int row = i / 28, k = i - row * 28;   // row = p*24+o
    sW[i] = (k < 27) ? ws_ro[row * 27 + k] : 0.f;
  }
  for (int i = tid; i < BEFF_FLOATS; i += 256) sB[i] = ws_ro[WEFF_FLOATS + i];
  __syncthreads();

  int bid = (int)blockIdx.x;
  int b = bid >> 7;
  int t = bid & 127;                 // 16 y-tiles x 8 x-tiles of 16x32
  int TYg = (t >> 3) * 16;
  int TXg = (t & 7) * 32;
  int hh = TYg + (tid >> 4);
  int ww0 = TXg + (tid & 15);        // second gaussian at ww0+16 (same parity)
  int p = (hh & 1) * 2 + (ww0 & 1);
  int hs = hh >> 1, ws0 = ww0 >> 1;  // ws1 = ws0 + 8

  const float* ib = inp + b * 3 * IH * IW;
  float in0[28], in1[28];
  in0[27] = 0.f; in1[27] = 0.f;
  #pragma unroll
  for (int cin = 0; cin < 3; ++cin) {
    #pragma unroll
    for (int ky = 0; ky < 3; ++ky) {
      int y = hs + ky - 1;
      bool yok = (y >= 0 && y < IH);
      #pragma unroll
      for (int kx = 0; kx < 3; ++kx) {
        int x0 = ws0 + kx - 1;
        int x1 = x0 + 8;             // >= 7, never < 0
        float v0 = 0.f, v1 = 0.f;
        if (yok && x0 >= 0 && x0 < IW) v0 = ib[(cin * IH + y) * IW + x0];
        if (yok && x1 < IW) v1 = ib[(cin * IH + y) * IW + x1];
        in0[cin * 9 + ky * 3 + kx] = v0;
        in1[cin * 9 + ky * 3 + kx] = v1;
      }
    }
  }

  float a0[24], a1[24];
  #pragma unroll
  for (int o = 0; o < 24; ++o) { float bi = sB[p * 24 + o]; a0[o] = bi; a1[o] = bi; }
  #pragma unroll
  for (int o = 0; o < 24; ++o) {
    const float4* wrow = (const float4*)&sW[(p * 24 + o) * 28];
    #pragma unroll
    for (int kq = 0; kq < 7; ++kq) {
      float4 w = wrow[kq];
      a0[o] = fmaf(in0[kq * 4 + 0], w.x, a0[o]);
      a0[o] = fmaf(in0[kq * 4 + 1], w.y, a0[o]);
      a0[o] = fmaf(in0[kq * 4 + 2], w.z, a0[o]);
      a0[o] = fmaf(in0[kq * 4 + 3], w.w, a0[o]);
      a1[o] = fmaf(in1[kq * 4 + 0], w.x, a1[o]);
      a1[o] = fmaf(in1[kq * 4 + 1], w.y, a1[o]);
      a1[o] = fmaf(in1[kq * 4 + 2], w.z, a1[o]);
      a1[o] = fmaf(in1[kq * 4 + 3], w.w, a1[o]);
    }
  }

  float2* posP = (float2*)(ws + POS_OFF);

  #pragma unroll
  for (int which = 0; which < 2; ++which) {
    const float* pr = which ? a1 : a0;
    int ww = which ? (ww0 + 16) : ww0;

    float l0 = pr[5], l1 = pr[11], l2 = pr[17], l3 = pr[23];
    float m = fmaxf(fmaxf(l0, l1), fmaxf(l2, l3));
    float e0 = __expf(l0 - m), e1 = __expf(l1 - m);
    float e2 = __expf(l2 - m), e3 = __expf(l3 - m);
    float inv = 1.f / (e0 + e1 + e2 + e3);
    float w0 = e0 * inv, w1 = e1 * inv, w2 = e2 * inv, w3 = e3 * inv;
    float cr = w0 * pr[0] + w1 * pr[6] + w2 * pr[12] + w3 * pr[18];
    float cg = w0 * pr[1] + w1 * pr[7] + w2 * pr[13] + w3 * pr[19];
    float cb = w0 * pr[2] + w1 * pr[8] + w2 * pr[14] + w3 * pr[20];
    float ox = w0 * fast_tanh(pr[3]) + w1 * fast_tanh(pr[9]) +
               w2 * fast_tanh(pr[15]) + w3 * fast_tanh(pr[21]);
    float oy = w0 * fast_tanh(pr[4]) + w1 * fast_tanh(pr[10]) +
               w2 * fast_tanh(pr[16]) + w3 * fast_tanh(pr[22]);

    // reference-order coordinate math (w=h=128, W=H=gw=gh=256)
    float coordx = ((float)ww / 256.f) * 2.f - 1.f;
    float coordy = ((float)hh / 256.f) * 2.f - 1.f;
    float x_ndc = coordx + 2.f * ox / 128.f - 1.f / 256.f;
    float y_ndc = coordy + 2.f * oy / 128.f - 1.f / 256.f;
    float cx = 0.5f * ((x_ndc + 1.f) * 256.f - 1.f);
    float cy = 0.5f * ((y_ndc + 1.f) * 256.f - 1.f);

    int g = (b << 16) | (hh << 8) | ww;
    posP[g] = make_float2(cy, cx);
    ws[CR_OFF + g] = cr;
    ws[CG_OFF + g] = cg;
    ws[CB_OFF + g] = cb;
  }
}

// 1024 blocks; 16x16 px tile, 1 px/thread, 8x8 candidate window with
// rr-threshold test (== reference alpha test). No atomics.
__global__ __launch_bounds__(256) void gather_kernel(
    const float* __restrict__ ws, float* __restrict__ out) {
  __shared__ float2 sPos[NREG];
  __shared__ float4 sCol[NREG];

  int tid = (int)threadIdx.x;
  int bid = (int)blockIdx.x;
  int b = bid >> 8;
  int t = bid & 255;
  int TY = (t >> 4) * TSY;
  int TX = (t & 15) * TSX;
  const float2* posP = (const float2*)(ws + POS_OFF);

  for (int i = tid; i < NREG; i += 256) {
    int r = i / GR, c = i - r * GR;
    int hh = TY - 2 + r, ww = TX - 2 + c;
    if ((unsigned)hh < GH && (unsigned)ww < GW) {
      int g = (b << 16) | (hh << 8) | ww;
      sPos[i] = posP[g];
      sCol[i] = make_float4(ws[CR_OFF + g], ws[CG_OFF + g], ws[CB_OFF + g], 0.f);
    } else {
      sPos[i] = make_float2(1e9f, 1e9f);
      sCol[i] = make_float4(0.f, 0.f, 0.f, 0.f);
    }
  }
  __syncthreads();

  int pxl = tid & 15, pyl = tid >> 4;
  float fpx = (float)(TX + pxl), fpy = (float)(TY + pyl);
  float ar = 0.f, ag = 0.f, ab = 0.f;

  #pragma unroll
  for (int ry = 0; ry < 8; ++ry) {
    int base = (pyl + ry) * GR + pxl;
    #pragma unroll
    for (int rx = 0; rx < 8; ++rx) {
      float2 P = sPos[base + rx];
      float dy = fpy - P.x;
      float dx = fpx - P.y;
      float rr = fmaf(dy, dy, dx * dx);
      if (rr < RR_MAX) {
        float al = fminf(0.999f, exp2f(EXP2C * rr));
        float4 C = sCol[base + rx];
        ar = fmaf(al, C.x, ar);
        ag = fmaf(al, C.y, ag);
        ab = fmaf(al, C.z, ab);
      }
    }
  }

  float* ob = out + b * 3 * GH * GW;
  int i0 = (TY + pyl) * GW + (TX + pxl);
  ob[i0] = clamp01(ar);
  ob[GH * GW + i0] = clamp01(ag);
  ob[2 * GH * GW + i0] = clamp01(ab);
}

extern "C" void kernel_launch(void* const* d_in, const int* in_sizes, int n_in,
                              void* d_out, int out_size, void* d_ws, size_t ws_size,
                              hipStream_t stream) {
  const float* inp = (const float*)d_in[0];
  const float* w_enc = (const float*)d_in[1];
  const float* b_enc = (const float*)d_in[2];
  const float* w_head = (const float*)d_in[3];
  const float* b_head = (const float*)d_in[4];
  // d_in[5] = scale (int), hardcoded 2.

  float* ws = (float*)d_ws;
  float* weff = ws;                  // [0, 2592)
  float* beff = ws + WEFF_FLOATS;    // [2592, 2688)

  weff_kernel<<<4, 256, 0, stream>>>(w_enc, b_enc, w_head, b_head, weff, beff);

  gauss_kernel<<<512, 256, 0, stream>>>(inp, ws, ws);

  gather_kernel<<<NB * 256, 256, 0, stream>>>(ws, (float*)d_out);
}